// Round 4
// baseline (765.426 us; speedup 1.0000x reference)
//
#include <hip/hip_runtime.h>
#include <hip/hip_bf16.h>
#include <cstdint>
#include <cstddef>

// ---------- types ----------
typedef __bf16 bf16x8 __attribute__((ext_vector_type(8)));
typedef float  f32x4  __attribute__((ext_vector_type(4)));

#define VOC   50000
#define W2    4224     // unified K: 4096 (kron weights) + 128 (concat weights)
#define XSTR  72       // LDS row stride in bf16 elems (16B-aligned rows)

// ---------- static device scratch ----------
__device__ __attribute__((aligned(256))) unsigned short g_vocT[(size_t)VOC * 64];
__device__ __attribute__((aligned(256))) unsigned short g_Xa[(size_t)131072 * 64]; // leaves / even levels
__device__ __attribute__((aligned(256))) unsigned short g_Xb[(size_t)65536 * 64];  // odd levels
__device__ __attribute__((aligned(256))) unsigned short g_roots[2048 * 64];
__device__ __attribute__((aligned(256))) unsigned short g_cpstU[64 * W2];  // [cpst_w | cps_w]
__device__ __attribute__((aligned(256))) unsigned short g_cprtU[64 * W2];  // [cprt_w | cpr_w]
__device__ float g_smw[7 * 64];
__device__ float g_smb[7];
__device__ float g_biasC[64];   // cps_b + cpst_b
__device__ float g_biasF[64];   // cpr_b + cprt_b

__device__ __forceinline__ float b2f(unsigned short u) {
    unsigned int x = ((unsigned int)u) << 16;
    return __builtin_bit_cast(float, x);
}
__device__ __forceinline__ unsigned short f2b(float f) {
    return __builtin_bit_cast(unsigned short, (__bf16)f);
}
__device__ __forceinline__ float scrub(float v) {
    return fminf(fmaxf(v, -64.f), 64.f);
}
__device__ __forceinline__ float ldf(const void* p, size_t i, int isb) {
    return isb ? b2f(((const unsigned short*)p)[i]) : ((const float*)p)[i];
}
// Per-WG dtype detection (no global flag -> no inter-kernel race).
__device__ __forceinline__ int detect_isb(const void* voc_b) {
    const unsigned int* p = (const unsigned int*)voc_b;
    int ok = 1;
    for (int k = 0; k < 32; k++) {
        float v = b2f((unsigned short)(p[k] & 0xFFFFu));
        if (!(fabsf(v) <= 0.0502f)) ok = 0;
    }
    return ok;
}

// ---------- kernel: canonicalize weights/biases into unified layouts ----------
__global__ __launch_bounds__(256) void k_convert(
    const void* voc_b,
    const void* cps_w, const void* cps_b, const void* cpst_w, const void* cpst_b,
    const void* cpr_w, const void* cpr_b, const void* cprt_w, const void* cprt_b,
    const void* sm_w, const void* sm_b)
{
    const int isb = detect_isb(voc_b);
    int gid = blockIdx.x * 256 + threadIdx.x;
    int stride = gridDim.x * 256;
    for (int i = gid; i < 64 * W2; i += stride) {
        int e = i / W2, c = i - e * W2;
        float v = (c < 4096) ? ldf(cpst_w, (size_t)e * 4096 + c, isb)
                             : ldf(cps_w,  (size_t)e * 128 + (c - 4096), isb);
        g_cpstU[i] = f2b(v);
    }
    for (int i = gid; i < 64 * W2; i += stride) {
        int e = i / W2, c = i - e * W2;
        float v = (c < 4096) ? ldf(cprt_w, (size_t)e * 4096 + c, isb)
                             : ldf(cpr_w,  (size_t)e * 128 + (c - 4096), isb);
        g_cprtU[i] = f2b(v);
    }
    for (int i = gid; i < 448; i += stride) g_smw[i] = ldf(sm_w, i, isb);
    if (gid < 64) {
        g_biasC[gid] = ldf(cps_b, gid, isb) + ldf(cpst_b, gid, isb);
        g_biasF[gid] = ldf(cpr_b, gid, isb) + ldf(cprt_b, gid, isb);
    }
    if (gid < 7) g_smb[gid] = ldf(sm_b, gid, isb);
}

// ---------- kernel: voc_w (64 x 50000) -> g_vocT[50000][64] bf16, fold voc_b ----------
__global__ __launch_bounds__(256) void k_vocT(const void* __restrict__ voc_w,
                                              const void* __restrict__ voc_b) {
    __shared__ float tile[64][65];
    __shared__ float vb[64];
    const int isb = detect_isb(voc_b);
    int t = threadIdx.x;
    if (t < 64) vb[t] = ldf(voc_b, t, isb);
    int v0 = blockIdx.x * 64;
    int vl = t & 63, dr = t >> 6;
    #pragma unroll
    for (int i = 0; i < 16; i++) {
        int d = dr * 16 + i;
        int v = v0 + vl;
        tile[vl][d] = (v < VOC) ? ldf(voc_w, (size_t)d * VOC + v, isb) : 0.f;
    }
    __syncthreads();
    int dl = t & 63, vr0 = t >> 6;
    #pragma unroll
    for (int i = 0; i < 16; i++) {
        int vr = vr0 * 16 + i;
        int v = v0 + vr;
        if (v < VOC) g_vocT[(size_t)v * 64 + dl] = f2b(tile[vr][dl] + vb[dl]);
    }
}

// ---------- kernel: gather leaf embeddings into g_Xa (131072 rows) ----------
__global__ __launch_bounds__(256) void k_leaves(const int* __restrict__ lleaf,
                                                const int* __restrict__ rleaf) {
    int r = blockIdx.x * 128 + (threadIdx.x >> 1);   // row
    int half = threadIdx.x & 1;
    int g = r >> 6, i = r & 63;
    int b = (g < 1024) ? g : g - 1024;
    const int* lv = (g < 1024) ? lleaf : rleaf;
    int idx = lv[b * 64 + i];
    idx = (idx < 0) ? 0 : ((idx >= VOC) ? VOC - 1 : idx);
    const int4* src = (const int4*)(g_vocT + (size_t)idx * 64 + half * 32);
    int4* dst = (int4*)(g_Xa + (size_t)r * 64 + half * 32);
    #pragma unroll
    for (int z = 0; z < 4; z++) dst[z] = src[z];
}

// ---------- B-fragment loader (unified 64 x 4224 weights) ----------
__device__ __forceinline__ void loadB(bf16x8 (&b)[4], const unsigned short* Bl, int kb) {
    #pragma unroll
    for (int nt = 0; nt < 4; nt++)
        b[nt] = *(const bf16x8*)(Bl + nt * 16 * W2 + kb * 32);
}

// ---------- kernel: one tree level as batched GEMM [M x 4224] @ [4224 x 64] ----------
// srcSel: 0=g_Xa 1=g_Xb ; dstSel: 0=g_Xa 1=g_Xb 2=g_roots
__global__ __launch_bounds__(256, 4) void k_level(int srcSel, int dstSel)
{
    __shared__ unsigned short Xs[128 * XSTR];   // 128 child rows
    __shared__ float biasC[64];
    const unsigned short* Xin = srcSel ? g_Xb : g_Xa;
    unsigned short* Xout = (dstSel == 2) ? g_roots : (dstSel ? g_Xb : g_Xa);
    const int tid = threadIdx.x;
    const int wgM0 = blockIdx.x * 64;
    if (tid < 64) biasC[tid] = g_biasC[tid];

    // stage 128 contiguous child rows (16 KB), coalesced
    {
        int row = tid >> 1, half = tid & 1;
        const int4* src = (const int4*)(Xin + ((size_t)(2 * wgM0 + row)) * 64 + half * 32);
        int4* dst = (int4*)(Xs + row * XSTR + half * 32);
        #pragma unroll
        for (int z = 0; z < 4; z++) dst[z] = src[z];
    }
    __syncthreads();

    const int lane = tid & 63, wave = tid >> 6;
    const int q = lane >> 4, sub = lane & 15;
    const int lm = wave * 16 + sub;             // this lane's A-row (local node)
    const unsigned short* rowL = Xs + (2 * lm) * XSTR;
    const unsigned short* rowR = Xs + (2 * lm + 1) * XSTR;

    // hoist the 4 octets this lane ever needs
    bf16x8 Lb0 = *(const bf16x8*)(rowL + q * 8);
    bf16x8 Lb1 = *(const bf16x8*)(rowL + 32 + q * 8);
    bf16x8 Rb0 = *(const bf16x8*)(rowR + q * 8);
    bf16x8 Rb1 = *(const bf16x8*)(rowR + 32 + q * 8);
    float Lf0[8], Lf1[8];
    #pragma unroll
    for (int z = 0; z < 8; z++) { Lf0[z] = (float)Lb0[z]; Lf1[z] = (float)Lb1[z]; }

    const unsigned short* Bl = g_cpstU + sub * W2 + q * 8;

    f32x4 acc[4];
    #pragma unroll
    for (int nt = 0; nt < 4; nt++)
        #pragma unroll
        for (int z = 0; z < 4; z++) acc[nt][z] = 0.f;

    bf16x8 b0[4], b1[4];
    loadB(b0, Bl, 0);
    float Lcur = b2f(rowL[0]);
    float Lnext = b2f(rowL[1]);
    for (int i = 0; i < 64; i++) {              // kron: kb = 2i, 2i+1
        loadB(b1, Bl, 2 * i + 1);
        bf16x8 afr;
        #pragma unroll
        for (int z = 0; z < 8; z++) afr[z] = (__bf16)(Lf0[z] * Lcur);
        #pragma unroll
        for (int nt = 0; nt < 4; nt++)
            acc[nt] = __builtin_amdgcn_mfma_f32_16x16x32_bf16(afr, b0[nt], acc[nt], 0, 0, 0);
        loadB(b0, Bl, 2 * i + 2);               // 2i+2 <= 130 < 132, always valid
        #pragma unroll
        for (int z = 0; z < 8; z++) afr[z] = (__bf16)(Lf1[z] * Lcur);
        #pragma unroll
        for (int nt = 0; nt < 4; nt++)
            acc[nt] = __builtin_amdgcn_mfma_f32_16x16x32_bf16(afr, b1[nt], acc[nt], 0, 0, 0);
        Lcur = Lnext;
        Lnext = b2f(rowL[i + 2]);               // i+2 <= 65 < XSTR pad, safe
    }
    // concat tail: kb 128..131 (b0 already holds kb=128)
    loadB(b1, Bl, 129);
    #pragma unroll
    for (int nt = 0; nt < 4; nt++) acc[nt] = __builtin_amdgcn_mfma_f32_16x16x32_bf16(Lb0, b0[nt], acc[nt], 0, 0, 0);
    loadB(b0, Bl, 130);
    #pragma unroll
    for (int nt = 0; nt < 4; nt++) acc[nt] = __builtin_amdgcn_mfma_f32_16x16x32_bf16(Lb1, b1[nt], acc[nt], 0, 0, 0);
    loadB(b1, Bl, 131);
    #pragma unroll
    for (int nt = 0; nt < 4; nt++) acc[nt] = __builtin_amdgcn_mfma_f32_16x16x32_bf16(Rb0, b0[nt], acc[nt], 0, 0, 0);
    #pragma unroll
    for (int nt = 0; nt < 4; nt++) acc[nt] = __builtin_amdgcn_mfma_f32_16x16x32_bf16(Rb1, b1[nt], acc[nt], 0, 0, 0);

    // epilogue: bias + tanh -> global
    #pragma unroll
    for (int nt = 0; nt < 4; nt++) {
        int e = nt * 16 + sub;                   // C col = lane&15
        #pragma unroll
        for (int r = 0; r < 4; r++) {
            int m = wgM0 + wave * 16 + q * 4 + r; // C row = quad*4 + reg
            Xout[(size_t)m * 64 + e] = f2b(tanhf(scrub(acc[nt][r] + biasC[e])));
        }
    }
}

// ---------- kernel: final cpr/cprt + leaky_relu + softmax ----------
__global__ __launch_bounds__(256) void k_final(const void* __restrict__ voc_b,
                                               void* __restrict__ out)
{
    __shared__ unsigned short Lv[64 * XSTR], Rv[64 * XSTR];
    __shared__ float actS[64][65];
    __shared__ float smw[7][64];
    __shared__ float smbS[7];
    __shared__ float biasF[64];
    const int tid = threadIdx.x, wg = blockIdx.x;
    const int isb = detect_isb(voc_b);
    if (tid < 64) biasF[tid] = g_biasF[tid];
    if (tid < 7)  smbS[tid] = g_smb[tid];
    for (int z = tid; z < 448; z += 256) smw[z >> 6][z & 63] = g_smw[z];

    {
        int row = tid >> 1, half = tid & 1;
        int item = row & 63; bool isR = row >= 64;
        const unsigned short* src = g_roots + (size_t)((isR ? 1024 : 0) + wg * 64 + item) * 64 + half * 32;
        unsigned short* dst = (isR ? Rv : Lv) + item * XSTR + half * 32;
        const int4* s4 = (const int4*)src; int4* d4 = (int4*)dst;
        #pragma unroll
        for (int z = 0; z < 4; z++) d4[z] = s4[z];
    }
    __syncthreads();

    const int lane = tid & 63, wave = tid >> 6;
    const int q = lane >> 4, sub = lane & 15;
    const int item = wave * 16 + sub;
    const unsigned short* rowL = Lv + item * XSTR;
    const unsigned short* rowR = Rv + item * XSTR;

    bf16x8 Lb0 = *(const bf16x8*)(rowL + q * 8);
    bf16x8 Lb1 = *(const bf16x8*)(rowL + 32 + q * 8);
    bf16x8 Rb0 = *(const bf16x8*)(rowR + q * 8);
    bf16x8 Rb1 = *(const bf16x8*)(rowR + 32 + q * 8);
    float Rf0[8], Rf1[8];                        // kron = l[i] * r[j]: octets from R
    #pragma unroll
    for (int z = 0; z < 8; z++) { Rf0[z] = (float)Rb0[z]; Rf1[z] = (float)Rb1[z]; }

    const unsigned short* Bl = g_cprtU + sub * W2 + q * 8;

    f32x4 acc[4];
    #pragma unroll
    for (int nt = 0; nt < 4; nt++)
        #pragma unroll
        for (int z = 0; z < 4; z++) acc[nt][z] = 0.f;

    bf16x8 b0[4], b1[4];
    loadB(b0, Bl, 0);
    float Lcur = b2f(rowL[0]);
    float Lnext = b2f(rowL[1]);
    for (int i = 0; i < 64; i++) {
        loadB(b1, Bl, 2 * i + 1);
        bf16x8 afr;
        #pragma unroll
        for (int z = 0; z < 8; z++) afr[z] = (__bf16)(Rf0[z] * Lcur);
        #pragma unroll
        for (int nt = 0; nt < 4; nt++)
            acc[nt] = __builtin_amdgcn_mfma_f32_16x16x32_bf16(afr, b0[nt], acc[nt], 0, 0, 0);
        loadB(b0, Bl, 2 * i + 2);
        #pragma unroll
        for (int z = 0; z < 8; z++) afr[z] = (__bf16)(Rf1[z] * Lcur);
        #pragma unroll
        for (int nt = 0; nt < 4; nt++)
            acc[nt] = __builtin_amdgcn_mfma_f32_16x16x32_bf16(afr, b1[nt], acc[nt], 0, 0, 0);
        Lcur = Lnext;
        Lnext = b2f(rowL[i + 2]);
    }
    loadB(b1, Bl, 129);
    #pragma unroll
    for (int nt = 0; nt < 4; nt++) acc[nt] = __builtin_amdgcn_mfma_f32_16x16x32_bf16(Lb0, b0[nt], acc[nt], 0, 0, 0);
    loadB(b0, Bl, 130);
    #pragma unroll
    for (int nt = 0; nt < 4; nt++) acc[nt] = __builtin_amdgcn_mfma_f32_16x16x32_bf16(Lb1, b1[nt], acc[nt], 0, 0, 0);
    loadB(b1, Bl, 131);
    #pragma unroll
    for (int nt = 0; nt < 4; nt++) acc[nt] = __builtin_amdgcn_mfma_f32_16x16x32_bf16(Rb0, b0[nt], acc[nt], 0, 0, 0);
    #pragma unroll
    for (int nt = 0; nt < 4; nt++) acc[nt] = __builtin_amdgcn_mfma_f32_16x16x32_bf16(Rb1, b1[nt], acc[nt], 0, 0, 0);

    #pragma unroll
    for (int nt = 0; nt < 4; nt++) {
        int e = nt * 16 + sub;
        #pragma unroll
        for (int r = 0; r < 4; r++) {
            int it = wave * 16 + q * 4 + r;
            float v = scrub(acc[nt][r] + biasF[e]);
            v = (v > 0.f) ? v : 0.01f * v;
            actS[it][e] = v;
        }
    }
    __syncthreads();

    if (tid < 64) {
        float lg[7];
        #pragma unroll
        for (int j = 0; j < 7; j++) lg[j] = smbS[j];
        for (int e = 0; e < 64; e++) {
            float a = actS[tid][e];
            #pragma unroll
            for (int j = 0; j < 7; j++) lg[j] += smw[j][e] * a;
        }
        float mx = lg[0];
        #pragma unroll
        for (int j = 1; j < 7; j++) mx = fmaxf(mx, lg[j]);
        float s = 0.f, p[7];
        #pragma unroll
        for (int j = 0; j < 7; j++) { p[j] = expf(lg[j] - mx); s += p[j]; }
        float inv = 1.f / s;
        size_t b = (size_t)wg * 64 + tid;
        if (isb) {
            unsigned short* o = (unsigned short*)out;
            #pragma unroll
            for (int j = 0; j < 7; j++) o[b * 7 + j] = f2b(p[j] * inv);
        } else {
            float* o = (float*)out;
            #pragma unroll
            for (int j = 0; j < 7; j++) o[b * 7 + j] = p[j] * inv;
        }
    }
}

// ---------- host launcher ----------
extern "C" void kernel_launch(void* const* d_in, const int* in_sizes, int n_in,
                              void* d_out, int out_size, void* d_ws, size_t ws_size,
                              hipStream_t stream) {
    const int* lleaf = (const int*)d_in[0];
    const int* rleaf = (const int*)d_in[1];
    const void* voc_w  = d_in[2];
    const void* voc_b  = d_in[3];
    const void* cps_w  = d_in[4];
    const void* cps_b  = d_in[5];
    const void* cpst_w = d_in[6];
    const void* cpst_b = d_in[7];
    const void* cpr_w  = d_in[8];
    const void* cpr_b  = d_in[9];
    const void* cprt_w = d_in[10];
    const void* cprt_b = d_in[11];
    const void* sm_w   = d_in[12];
    const void* sm_b   = d_in[13];

    k_convert<<<512, 256, 0, stream>>>(voc_b, cps_w, cps_b, cpst_w, cpst_b,
                                       cpr_w, cpr_b, cprt_w, cprt_b, sm_w, sm_b);
    k_vocT<<<(VOC + 63) / 64, 256, 0, stream>>>(voc_w, voc_b);
    k_leaves<<<1024, 256, 0, stream>>>(lleaf, rleaf);

    // levels: (src, dst, M): L5 A->B 65536, L4 B->A 32768, L3 A->B 16384,
    //         L2 B->A 8192, L1 A->B 4096, L0 B->roots 2048
    k_level<<<1024, 256, 0, stream>>>(0, 1);
    k_level<<< 512, 256, 0, stream>>>(1, 0);
    k_level<<< 256, 256, 0, stream>>>(0, 1);
    k_level<<< 128, 256, 0, stream>>>(1, 0);
    k_level<<<  64, 256, 0, stream>>>(0, 1);
    k_level<<<  32, 256, 0, stream>>>(1, 2);

    k_final<<<16, 256, 0, stream>>>(voc_b, (unsigned short*)d_out);
}

// Round 5
// 501.848 us; speedup vs baseline: 1.5252x; 1.5252x over previous
//
#include <hip/hip_runtime.h>
#include <hip/hip_bf16.h>
#include <cstdint>
#include <cstddef>

// ---------- types ----------
typedef __bf16 bf16x8 __attribute__((ext_vector_type(8)));
typedef float  f32x4  __attribute__((ext_vector_type(4)));

#define VOC   50000
#define W2    4224     // unified K: 4096 (kron weights) + 128 (concat weights)
#define XSTR  72       // LDS row stride in bf16 elems (16B-aligned rows)

// ---------- static device scratch ----------
__device__ __attribute__((aligned(256))) unsigned short g_vocT[(size_t)VOC * 64];
__device__ __attribute__((aligned(256))) unsigned short g_Xa[(size_t)131072 * 64]; // leaves / even levels
__device__ __attribute__((aligned(256))) unsigned short g_Xb[(size_t)65536 * 64];  // odd levels
__device__ __attribute__((aligned(256))) unsigned short g_roots[2048 * 64];
__device__ __attribute__((aligned(256))) unsigned short g_cpstU[64 * W2];  // [cpst_w | cps_w]
__device__ __attribute__((aligned(256))) unsigned short g_cprtU[64 * W2];  // [cprt_w | cpr_w]
__device__ float g_smw[7 * 64];
__device__ float g_smb[7];
__device__ float g_biasC[64];   // cps_b + cpst_b
__device__ float g_biasF[64];   // cpr_b + cprt_b

__device__ __forceinline__ float b2f(unsigned short u) {
    unsigned int x = ((unsigned int)u) << 16;
    return __builtin_bit_cast(float, x);
}
__device__ __forceinline__ unsigned short f2b(float f) {
    return __builtin_bit_cast(unsigned short, (__bf16)f);
}
__device__ __forceinline__ float scrub(float v) {
    return fminf(fmaxf(v, -64.f), 64.f);
}
__device__ __forceinline__ float ldf(const void* p, size_t i, int isb) {
    return isb ? b2f(((const unsigned short*)p)[i]) : ((const float*)p)[i];
}
__device__ __forceinline__ int detect_isb(const void* voc_b) {
    const unsigned int* p = (const unsigned int*)voc_b;
    int ok = 1;
    for (int k = 0; k < 32; k++) {
        float v = b2f((unsigned short)(p[k] & 0xFFFFu));
        if (!(fabsf(v) <= 0.0502f)) ok = 0;
    }
    return ok;
}

// ---------- kernel: canonicalize weights/biases into unified layouts ----------
__global__ __launch_bounds__(256) void k_convert(
    const void* voc_b,
    const void* cps_w, const void* cps_b, const void* cpst_w, const void* cpst_b,
    const void* cpr_w, const void* cpr_b, const void* cprt_w, const void* cprt_b,
    const void* sm_w, const void* sm_b)
{
    const int isb = detect_isb(voc_b);
    int gid = blockIdx.x * 256 + threadIdx.x;
    int stride = gridDim.x * 256;
    for (int i = gid; i < 64 * W2; i += stride) {
        int e = i / W2, c = i - e * W2;
        float v = (c < 4096) ? ldf(cpst_w, (size_t)e * 4096 + c, isb)
                             : ldf(cps_w,  (size_t)e * 128 + (c - 4096), isb);
        g_cpstU[i] = f2b(v);
    }
    for (int i = gid; i < 64 * W2; i += stride) {
        int e = i / W2, c = i - e * W2;
        float v = (c < 4096) ? ldf(cprt_w, (size_t)e * 4096 + c, isb)
                             : ldf(cpr_w,  (size_t)e * 128 + (c - 4096), isb);
        g_cprtU[i] = f2b(v);
    }
    for (int i = gid; i < 448; i += stride) g_smw[i] = ldf(sm_w, i, isb);
    if (gid < 64) {
        g_biasC[gid] = ldf(cps_b, gid, isb) + ldf(cpst_b, gid, isb);
        g_biasF[gid] = ldf(cpr_b, gid, isb) + ldf(cprt_b, gid, isb);
    }
    if (gid < 7) g_smb[gid] = ldf(sm_b, gid, isb);
}

// ---------- kernel: voc_w (64 x 50000) -> g_vocT[50000][64] bf16, fold voc_b ----------
__global__ __launch_bounds__(256) void k_vocT(const void* __restrict__ voc_w,
                                              const void* __restrict__ voc_b) {
    __shared__ float tile[64][65];
    __shared__ float vb[64];
    const int isb = detect_isb(voc_b);
    int t = threadIdx.x;
    if (t < 64) vb[t] = ldf(voc_b, t, isb);
    int v0 = blockIdx.x * 64;
    int vl = t & 63, dr = t >> 6;
    #pragma unroll
    for (int i = 0; i < 16; i++) {
        int d = dr * 16 + i;
        int v = v0 + vl;
        tile[vl][d] = (v < VOC) ? ldf(voc_w, (size_t)d * VOC + v, isb) : 0.f;
    }
    __syncthreads();
    int dl = t & 63, vr0 = t >> 6;
    #pragma unroll
    for (int i = 0; i < 16; i++) {
        int vr = vr0 * 16 + i;
        int v = v0 + vr;
        if (v < VOC) g_vocT[(size_t)v * 64 + dl] = f2b(tile[vr][dl] + vb[dl]);
    }
}

// ---------- kernel: gather leaf embeddings into g_Xa (131072 rows) ----------
__global__ __launch_bounds__(256) void k_leaves(const int* __restrict__ lleaf,
                                                const int* __restrict__ rleaf) {
    int r = blockIdx.x * 128 + (threadIdx.x >> 1);
    int half = threadIdx.x & 1;
    int g = r >> 6, i = r & 63;
    int b = (g < 1024) ? g : g - 1024;
    const int* lv = (g < 1024) ? lleaf : rleaf;
    int idx = lv[b * 64 + i];
    idx = (idx < 0) ? 0 : ((idx >= VOC) ? VOC - 1 : idx);
    const uint4* src = (const uint4*)(g_vocT + (size_t)idx * 64 + half * 32);
    uint4* dst = (uint4*)(g_Xa + (size_t)r * 64 + half * 32);
    #pragma unroll
    for (int z = 0; z < 4; z++) dst[z] = src[z];
}

// ---------- kernel: one tree level as batched GEMM [M x 4224] @ [4224 x 64] ----------
// B staged through LDS in 4-kb (16 KB) double-buffered stages shared by all 4 waves.
// srcSel: 0=g_Xa 1=g_Xb ; dstSel: 0=g_Xa 1=g_Xb 2=g_roots
template<int CH>
__global__ __launch_bounds__(256, (CH == 2 ? 2 : 3)) void k_level(int srcSel, int dstSel)
{
    __shared__ __attribute__((aligned(16))) unsigned short Xs[128 * CH * XSTR]; // child rows
    __shared__ __attribute__((aligned(16))) unsigned short Bs[2][4 * 64 * 32];  // 2 x 16KB B stages
    __shared__ float biasC[64];
    const unsigned short* Xin = srcSel ? g_Xb : g_Xa;
    unsigned short* Xout = (dstSel == 2) ? g_roots : (dstSel ? g_Xb : g_Xa);
    const int tid = threadIdx.x;
    const int M0 = blockIdx.x * (64 * CH);
    if (tid < 64) biasC[tid] = g_biasC[tid];

    // ---- stage child rows (2*64*CH rows x 128 B), coalesced ----
    #pragma unroll
    for (int it = 0; it < CH; it++) {
        int task = it * 256 + tid;
        int row = task >> 1, half = task & 1;
        const uint4* src = (const uint4*)(Xin + ((size_t)(2 * M0 + row)) * 64 + half * 32);
        uint4* dst = (uint4*)(Xs + row * XSTR + half * 32);
        #pragma unroll
        for (int z = 0; z < 4; z++) dst[z] = src[z];
    }

    // ---- issue B stage 0 load (in flight across the barrier) ----
    const int bn = tid >> 2, bko = (tid & 3) * 8;
    const unsigned short* Wrow = g_cpstU + (size_t)bn * W2 + bko;
    uint4 r[4];
    #pragma unroll
    for (int kbl = 0; kbl < 4; kbl++)
        r[kbl] = *(const uint4*)(Wrow + kbl * 32);

    __syncthreads();   // Xs visible (stage-0 loads drained here too)

    const int lane = tid & 63, wave = tid >> 6;
    const int q = lane >> 4, sub = lane & 15;

    int rowLo[CH];
    float Lf[CH][2][8];
    #pragma unroll
    for (int c = 0; c < CH; c++) {
        rowLo[c] = (2 * ((wave * CH + c) * 16 + sub)) * XSTR;
        bf16x8 o0 = *(const bf16x8*)(Xs + rowLo[c] + q * 8);
        bf16x8 o1 = *(const bf16x8*)(Xs + rowLo[c] + 32 + q * 8);
        #pragma unroll
        for (int z = 0; z < 8; z++) { Lf[c][0][z] = (float)o0[z]; Lf[c][1][z] = (float)o1[z]; }
    }

    f32x4 acc[CH][4];
    #pragma unroll
    for (int c = 0; c < CH; c++)
        #pragma unroll
        for (int nt = 0; nt < 4; nt++)
            #pragma unroll
            for (int z = 0; z < 4; z++) acc[c][nt][z] = 0.f;

    // ---- 33 stages x 4 kb: kron (s=0..31), concat tail (s=32) ----
    for (int s = 0; s < 33; s++) {
        // publish stage s (regs -> LDS), shared by all waves
        {
            unsigned short* dst = Bs[s & 1] + tid * 8;
            #pragma unroll
            for (int kbl = 0; kbl < 4; kbl++)
                *(uint4*)(dst + kbl * 2048) = r[kbl];
        }
        __syncthreads();   // stage s visible
        if (s < 32) {      // prefetch stage s+1 (lands during compute below)
            #pragma unroll
            for (int kbl = 0; kbl < 4; kbl++)
                r[kbl] = *(const uint4*)(Wrow + (size_t)(4 * (s + 1) + kbl) * 32);
        }
        const unsigned short* Bp = Bs[s & 1];
        if (s < 32) {
            #pragma unroll
            for (int ii = 0; ii < 2; ii++) {
                int i = 2 * s + ii;
                float Li[CH];
                #pragma unroll
                for (int c = 0; c < CH; c++) Li[c] = b2f(Xs[rowLo[c] + i]);
                #pragma unroll
                for (int p2 = 0; p2 < 2; p2++) {
                    int kbl = 2 * ii + p2;
                    bf16x8 bfr[4];
                    #pragma unroll
                    for (int nt = 0; nt < 4; nt++)
                        bfr[nt] = *(const bf16x8*)(Bp + kbl * 2048 + (nt * 16 + sub) * 32 + q * 8);
                    #pragma unroll
                    for (int c = 0; c < CH; c++) {
                        bf16x8 afr;
                        #pragma unroll
                        for (int z = 0; z < 8; z++) afr[z] = (__bf16)(Lf[c][p2][z] * Li[c]);
                        #pragma unroll
                        for (int nt = 0; nt < 4; nt++)
                            acc[c][nt] = __builtin_amdgcn_mfma_f32_16x16x32_bf16(afr, bfr[nt], acc[c][nt], 0, 0, 0);
                    }
                }
            }
        } else {           // concat(L,R): kb 128..131
            bf16x8 A4[CH][4];
            #pragma unroll
            for (int c = 0; c < CH; c++) {
                A4[c][0] = *(const bf16x8*)(Xs + rowLo[c] + q * 8);
                A4[c][1] = *(const bf16x8*)(Xs + rowLo[c] + 32 + q * 8);
                A4[c][2] = *(const bf16x8*)(Xs + rowLo[c] + XSTR + q * 8);
                A4[c][3] = *(const bf16x8*)(Xs + rowLo[c] + XSTR + 32 + q * 8);
            }
            #pragma unroll
            for (int kbl = 0; kbl < 4; kbl++) {
                bf16x8 bfr[4];
                #pragma unroll
                for (int nt = 0; nt < 4; nt++)
                    bfr[nt] = *(const bf16x8*)(Bp + kbl * 2048 + (nt * 16 + sub) * 32 + q * 8);
                #pragma unroll
                for (int c = 0; c < CH; c++)
                    #pragma unroll
                    for (int nt = 0; nt < 4; nt++)
                        acc[c][nt] = __builtin_amdgcn_mfma_f32_16x16x32_bf16(A4[c][kbl], bfr[nt], acc[c][nt], 0, 0, 0);
            }
        }
        __syncthreads();   // all waves done reading Bs[s&1] before overwrite at s+2
    }

    // ---- epilogue: bias + tanh -> global ----
    #pragma unroll
    for (int c = 0; c < CH; c++)
        #pragma unroll
        for (int nt = 0; nt < 4; nt++) {
            int e = nt * 16 + sub;
            #pragma unroll
            for (int rr = 0; rr < 4; rr++) {
                int m = M0 + (wave * CH + c) * 16 + q * 4 + rr;
                Xout[(size_t)m * 64 + e] = f2b(tanhf(scrub(acc[c][nt][rr] + biasC[e])));
            }
        }
}

// ---------- kernel: final cpr/cprt + leaky_relu + softmax (same staged-B pipeline) ----------
__global__ __launch_bounds__(256, 2) void k_final(const void* __restrict__ voc_b,
                                                  void* __restrict__ out)
{
    __shared__ __attribute__((aligned(16))) unsigned short Lv[64 * XSTR], Rv[64 * XSTR];
    __shared__ __attribute__((aligned(16))) unsigned short Bs[2][4 * 64 * 32];
    __shared__ float actS[64][65];
    __shared__ float smw[7][64];
    __shared__ float smbS[7];
    __shared__ float biasF[64];
    const int tid = threadIdx.x, wg = blockIdx.x;
    const int isb = detect_isb(voc_b);
    if (tid < 64) biasF[tid] = g_biasF[tid];
    if (tid < 7)  smbS[tid] = g_smb[tid];
    for (int z = tid; z < 448; z += 256) smw[z >> 6][z & 63] = g_smw[z];

    {   // stage l and r roots for this WG's 64 items
        int row = tid >> 1, half = tid & 1;
        int item = row & 63; bool isR = row >= 64;
        const unsigned short* src = g_roots + (size_t)((isR ? 1024 : 0) + wg * 64 + item) * 64 + half * 32;
        unsigned short* dst = (isR ? Rv : Lv) + item * XSTR + half * 32;
        const uint4* s4 = (const uint4*)src; uint4* d4 = (uint4*)dst;
        #pragma unroll
        for (int z = 0; z < 4; z++) d4[z] = s4[z];
    }

    const int bn = tid >> 2, bko = (tid & 3) * 8;
    const unsigned short* Wrow = g_cprtU + (size_t)bn * W2 + bko;
    uint4 r[4];
    #pragma unroll
    for (int kbl = 0; kbl < 4; kbl++)
        r[kbl] = *(const uint4*)(Wrow + kbl * 32);

    __syncthreads();

    const int lane = tid & 63, wave = tid >> 6;
    const int q = lane >> 4, sub = lane & 15;
    const int item = wave * 16 + sub;
    const int rowLo = item * XSTR;

    // kron = l[i] * r[j]: octets from R, scalar stream from L
    float Rf[2][8];
    {
        bf16x8 o0 = *(const bf16x8*)(Rv + rowLo + q * 8);
        bf16x8 o1 = *(const bf16x8*)(Rv + rowLo + 32 + q * 8);
        #pragma unroll
        for (int z = 0; z < 8; z++) { Rf[0][z] = (float)o0[z]; Rf[1][z] = (float)o1[z]; }
    }

    f32x4 acc[4];
    #pragma unroll
    for (int nt = 0; nt < 4; nt++)
        #pragma unroll
        for (int z = 0; z < 4; z++) acc[nt][z] = 0.f;

    for (int s = 0; s < 33; s++) {
        {
            unsigned short* dst = Bs[s & 1] + tid * 8;
            #pragma unroll
            for (int kbl = 0; kbl < 4; kbl++)
                *(uint4*)(dst + kbl * 2048) = r[kbl];
        }
        __syncthreads();
        if (s < 32) {
            #pragma unroll
            for (int kbl = 0; kbl < 4; kbl++)
                r[kbl] = *(const uint4*)(Wrow + (size_t)(4 * (s + 1) + kbl) * 32);
        }
        const unsigned short* Bp = Bs[s & 1];
        if (s < 32) {
            #pragma unroll
            for (int ii = 0; ii < 2; ii++) {
                int i = 2 * s + ii;
                float Li = b2f(Lv[rowLo + i]);
                #pragma unroll
                for (int p2 = 0; p2 < 2; p2++) {
                    int kbl = 2 * ii + p2;
                    bf16x8 bfr[4];
                    #pragma unroll
                    for (int nt = 0; nt < 4; nt++)
                        bfr[nt] = *(const bf16x8*)(Bp + kbl * 2048 + (nt * 16 + sub) * 32 + q * 8);
                    bf16x8 afr;
                    #pragma unroll
                    for (int z = 0; z < 8; z++) afr[z] = (__bf16)(Rf[p2][z] * Li);
                    #pragma unroll
                    for (int nt = 0; nt < 4; nt++)
                        acc[nt] = __builtin_amdgcn_mfma_f32_16x16x32_bf16(afr, bfr[nt], acc[nt], 0, 0, 0);
                }
            }
        } else {           // concat(l, r): kb 128..131
            bf16x8 A4[4];
            A4[0] = *(const bf16x8*)(Lv + rowLo + q * 8);
            A4[1] = *(const bf16x8*)(Lv + rowLo + 32 + q * 8);
            A4[2] = *(const bf16x8*)(Rv + rowLo + q * 8);
            A4[3] = *(const bf16x8*)(Rv + rowLo + 32 + q * 8);
            #pragma unroll
            for (int kbl = 0; kbl < 4; kbl++) {
                bf16x8 bfr[4];
                #pragma unroll
                for (int nt = 0; nt < 4; nt++)
                    bfr[nt] = *(const bf16x8*)(Bp + kbl * 2048 + (nt * 16 + sub) * 32 + q * 8);
                #pragma unroll
                for (int nt = 0; nt < 4; nt++)
                    acc[nt] = __builtin_amdgcn_mfma_f32_16x16x32_bf16(A4[kbl], bfr[nt], acc[nt], 0, 0, 0);
            }
        }
        __syncthreads();
    }

    // epilogue: bias + leaky_relu -> LDS
    #pragma unroll
    for (int nt = 0; nt < 4; nt++) {
        int e = nt * 16 + sub;
        #pragma unroll
        for (int rr = 0; rr < 4; rr++) {
            int it = wave * 16 + q * 4 + rr;
            float v = scrub(acc[nt][rr] + biasF[e]);
            v = (v > 0.f) ? v : 0.01f * v;
            actS[it][e] = v;
        }
    }
    __syncthreads();

    if (tid < 64) {
        float lg[7];
        #pragma unroll
        for (int j = 0; j < 7; j++) lg[j] = smbS[j];
        for (int e = 0; e < 64; e++) {
            float a = actS[tid][e];
            #pragma unroll
            for (int j = 0; j < 7; j++) lg[j] += smw[j][e] * a;
        }
        float mx = lg[0];
        #pragma unroll
        for (int j = 1; j < 7; j++) mx = fmaxf(mx, lg[j]);
        float s = 0.f, p[7];
        #pragma unroll
        for (int j = 0; j < 7; j++) { p[j] = expf(lg[j] - mx); s += p[j]; }
        float inv = 1.f / s;
        size_t b = (size_t)wg * 64 + tid;
        if (isb) {
            unsigned short* o = (unsigned short*)out;
            #pragma unroll
            for (int j = 0; j < 7; j++) o[b * 7 + j] = f2b(p[j] * inv);
        } else {
            float* o = (float*)out;
            #pragma unroll
            for (int j = 0; j < 7; j++) o[b * 7 + j] = p[j] * inv;
        }
    }
}

// ---------- host launcher ----------
extern "C" void kernel_launch(void* const* d_in, const int* in_sizes, int n_in,
                              void* d_out, int out_size, void* d_ws, size_t ws_size,
                              hipStream_t stream) {
    const int* lleaf = (const int*)d_in[0];
    const int* rleaf = (const int*)d_in[1];
    const void* voc_w  = d_in[2];
    const void* voc_b  = d_in[3];
    const void* cps_w  = d_in[4];
    const void* cps_b  = d_in[5];
    const void* cpst_w = d_in[6];
    const void* cpst_b = d_in[7];
    const void* cpr_w  = d_in[8];
    const void* cpr_b  = d_in[9];
    const void* cprt_w = d_in[10];
    const void* cprt_b = d_in[11];
    const void* sm_w   = d_in[12];
    const void* sm_b   = d_in[13];

    k_convert<<<512, 256, 0, stream>>>(voc_b, cps_w, cps_b, cpst_w, cpst_b,
                                       cpr_w, cpr_b, cprt_w, cprt_b, sm_w, sm_b);
    k_vocT<<<(VOC + 63) / 64, 256, 0, stream>>>(voc_w, voc_b);
    k_leaves<<<1024, 256, 0, stream>>>(lleaf, rleaf);

    // levels (src, dst): L5 A->B M=65536, L4 B->A 32768, L3 A->B 16384,
    //                    L2 B->A 8192, L1 A->B 4096, L0 B->roots 2048
    k_level<2><<<512, 256, 0, stream>>>(0, 1);
    k_level<2><<<256, 256, 0, stream>>>(1, 0);
    k_level<2><<<128, 256, 0, stream>>>(0, 1);
    k_level<1><<<128, 256, 0, stream>>>(1, 0);
    k_level<1><<< 64, 256, 0, stream>>>(0, 1);
    k_level<1><<< 32, 256, 0, stream>>>(1, 2);

    k_final<<<16, 256, 0, stream>>>(voc_b, (unsigned short*)d_out);
}

// Round 6
// 307.049 us; speedup vs baseline: 2.4928x; 1.6344x over previous
//
#include <hip/hip_runtime.h>
#include <hip/hip_bf16.h>
#include <cstdint>
#include <cstddef>

// ---------- types ----------
typedef __bf16 bf16x8 __attribute__((ext_vector_type(8)));
typedef float  f32x4  __attribute__((ext_vector_type(4)));

#define VOC    50000
#define W2     4224      // unified K: 4096 (kron) + 128 (concat)
#define NSTAGE 33        // 33 stages x 128 k = 4224
#define STG    8192      // elems per stage (128 k x 64 n) = 16 KB
#define XSTR   72        // LDS row stride in bf16 elems (144 B, 16B-aligned)
#define TPW    8         // trees per WG in k_tree

// ---------- static device scratch ----------
__device__ __attribute__((aligned(256))) unsigned short g_vocT[(size_t)VOC * 64];
__device__ __attribute__((aligned(256))) unsigned short g_roots[2048 * 64];
// weights in stage-fragment order: d = s*8192 + kbl*2048 + q*512 + n*8 + z
// maps to W[n][k], k = s*128 + kbl*32 + q*8 + z
__device__ __attribute__((aligned(256))) unsigned short g_cpstU[64 * W2];
__device__ __attribute__((aligned(256))) unsigned short g_cprtU[64 * W2];
__device__ float g_smw[7 * 64];
__device__ float g_smb[7];
__device__ float g_biasC[64];   // cps_b + cpst_b
__device__ float g_biasF[64];   // cpr_b + cprt_b

__device__ __forceinline__ float b2f(unsigned short u) {
    unsigned int x = ((unsigned int)u) << 16;
    return __builtin_bit_cast(float, x);
}
__device__ __forceinline__ unsigned short f2b(float f) {
    return __builtin_bit_cast(unsigned short, (__bf16)f);
}
__device__ __forceinline__ float scrub(float v) {
    return fminf(fmaxf(v, -64.f), 64.f);
}
__device__ __forceinline__ float ldf(const void* p, size_t i, int isb) {
    return isb ? b2f(((const unsigned short*)p)[i]) : ((const float*)p)[i];
}
__device__ __forceinline__ int detect_isb(const void* voc_b) {
    const unsigned int* p = (const unsigned int*)voc_b;
    int ok = 1;
    for (int k = 0; k < 32; k++) {
        float v = b2f((unsigned short)(p[k] & 0xFFFFu));
        if (!(fabsf(v) <= 0.0502f)) ok = 0;
    }
    return ok;
}

// ---------- kernel: canonicalize weights into stage-fragment order ----------
__global__ __launch_bounds__(256) void k_convert(
    const void* voc_b,
    const void* cps_w, const void* cps_b, const void* cpst_w, const void* cpst_b,
    const void* cpr_w, const void* cpr_b, const void* cprt_w, const void* cprt_b,
    const void* sm_w, const void* sm_b)
{
    const int isb = detect_isb(voc_b);
    int gid = blockIdx.x * 256 + threadIdx.x;
    int stride = gridDim.x * 256;
    for (int d = gid; d < 64 * W2; d += stride) {
        int s    = d / STG;
        int rem  = d - s * STG;
        int kbl  = rem >> 11;
        int rem2 = rem & 2047;
        int q    = rem2 >> 9;
        int rem3 = rem2 & 511;
        int n    = rem3 >> 3;
        int z    = rem3 & 7;
        int k    = s * 128 + kbl * 32 + q * 8 + z;
        float v1 = (k < 4096) ? ldf(cpst_w, (size_t)n * 4096 + k, isb)
                              : ldf(cps_w,  (size_t)n * 128 + (k - 4096), isb);
        g_cpstU[d] = f2b(v1);
        float v2 = (k < 4096) ? ldf(cprt_w, (size_t)n * 4096 + k, isb)
                              : ldf(cpr_w,  (size_t)n * 128 + (k - 4096), isb);
        g_cprtU[d] = f2b(v2);
    }
    for (int i = gid; i < 448; i += stride) g_smw[i] = ldf(sm_w, i, isb);
    if (gid < 64) {
        g_biasC[gid] = ldf(cps_b, gid, isb) + ldf(cpst_b, gid, isb);
        g_biasF[gid] = ldf(cpr_b, gid, isb) + ldf(cprt_b, gid, isb);
    }
    if (gid < 7) g_smb[gid] = ldf(sm_b, gid, isb);
}

// ---------- kernel: voc_w (64 x 50000) -> g_vocT[50000][64] bf16, fold voc_b ----------
__global__ __launch_bounds__(256) void k_vocT(const void* __restrict__ voc_w,
                                              const void* __restrict__ voc_b) {
    __shared__ float tile[64][65];
    __shared__ float vb[64];
    const int isb = detect_isb(voc_b);
    int t = threadIdx.x;
    if (t < 64) vb[t] = ldf(voc_b, t, isb);
    int v0 = blockIdx.x * 64;
    int vl = t & 63, dr = t >> 6;
    #pragma unroll
    for (int i = 0; i < 16; i++) {
        int d = dr * 16 + i;
        int v = v0 + vl;
        tile[vl][d] = (v < VOC) ? ldf(voc_w, (size_t)d * VOC + v, isb) : 0.f;
    }
    __syncthreads();
    int dl = t & 63, vr0 = t >> 6;
    #pragma unroll
    for (int i = 0; i < 16; i++) {
        int vr = vr0 * 16 + i;
        int v = v0 + vr;
        if (v < VOC) g_vocT[(size_t)v * 64 + dl] = f2b(tile[vr][dl] + vb[dl]);
    }
}

// ---------- kernel: full tree composition, 8 trees per WG, all levels in LDS ----------
__global__ __launch_bounds__(512, 1) void k_tree(const int* __restrict__ lleaf,
                                                 const int* __restrict__ rleaf)
{
    __shared__ __attribute__((aligned(16))) unsigned short Xs[512 * XSTR];  // 73728 B
    __shared__ __attribute__((aligned(16))) unsigned short Bs[2][STG];      // 32768 B
    __shared__ float biasC[64];
    const int tid = threadIdx.x;
    const int wg  = blockIdx.x;
    if (tid < 64) biasC[tid] = g_biasC[tid];

    // ---- leaf gather: row tid = (tree tid>>6, leaf tid&63) ----
    {
        int t = tid >> 6, i = tid & 63;
        int g = wg * TPW + t;                    // 0..1023 left, 1024..2047 right
        int b = (g < 1024) ? g : g - 1024;
        const int* lv = (g < 1024) ? lleaf : rleaf;
        int idx = lv[b * 64 + i];
        idx = (idx < 0) ? 0 : ((idx >= VOC) ? VOC - 1 : idx);
        const uint4* src = (const uint4*)(g_vocT + (size_t)idx * 64);
        uint4* dst = (uint4*)(Xs + tid * XSTR);
        #pragma unroll
        for (int z = 0; z < 8; z++) dst[z] = src[z];
    }

    // ---- prefetch weight stage 0 (linear, coalesced) ----
    uint4 r0 = *(const uint4*)(g_cpstU + (size_t)tid * 8);
    uint4 r1 = *(const uint4*)(g_cpstU + 4096 + (size_t)tid * 8);

    __syncthreads();   // Xs ready

    const int lane = tid & 63, wave = tid >> 6;
    const int q = lane >> 4, sub = lane & 15;

    for (int lv = 0; lv < 6; lv++) {
        const int lg = 5 - lv;                   // outputs per tree = 1<<lg
        const int cnew = 1 << lg;
        const int nodes = TPW << lg;             // 256,128,64,32,16,8
        const int nchunks = (nodes + 15) >> 4;   // 16,8,4,2,1,1
        const int chpw = (nchunks > 8) ? 2 : 1;

        int act[2], slotL[2];
        float Lf[2][2][8];
        #pragma unroll
        for (int c = 0; c < 2; c++) {
            int ch = wave * chpw + c;
            act[c] = (c < chpw) && (ch < nchunks);
            int m = ch * 16 + sub; if (m >= nodes) m = 0;
            int t = m >> lg, n = m & (cnew - 1);
            slotL[c] = (t * 64 + 2 * n) * XSTR;
            bf16x8 o0 = *(const bf16x8*)(Xs + slotL[c] + q * 8);
            bf16x8 o1 = *(const bf16x8*)(Xs + slotL[c] + 32 + q * 8);
            #pragma unroll
            for (int z = 0; z < 8; z++) { Lf[c][0][z] = (float)o0[z]; Lf[c][1][z] = (float)o1[z]; }
        }

        f32x4 acc[2][4];
        #pragma unroll
        for (int c = 0; c < 2; c++)
            #pragma unroll
            for (int nt = 0; nt < 4; nt++)
                #pragma unroll
                for (int z = 0; z < 4; z++) acc[c][nt][z] = 0.f;

        for (int s = 0; s < NSTAGE; s++) {
            const int par = (lv * NSTAGE + s) & 1;
            // publish stage s (regs -> LDS, conflict-free linear)
            *(uint4*)(Bs[par] + tid * 8) = r0;
            *(uint4*)(Bs[par] + 4096 + tid * 8) = r1;
            __syncthreads();
            // prefetch next stage (wraps to 0 across level boundary: same weights)
            {
                int sn = (s == NSTAGE - 1) ? 0 : s + 1;
                const unsigned short* base = g_cpstU + (size_t)sn * STG;
                r0 = *(const uint4*)(base + tid * 8);
                r1 = *(const uint4*)(base + 4096 + tid * 8);
            }
            const unsigned short* Bp = Bs[par];
            if (s < 32) {                        // kron: kb = 4s..4s+3
                #pragma unroll
                for (int ii = 0; ii < 2; ii++) {
                    int i = 2 * s + ii;
                    float Li[2];
                    #pragma unroll
                    for (int c = 0; c < 2; c++) Li[c] = b2f(Xs[slotL[c] + i]);
                    #pragma unroll
                    for (int p2 = 0; p2 < 2; p2++) {
                        int kbl = 2 * ii + p2;
                        bf16x8 bfr[4];
                        #pragma unroll
                        for (int nt = 0; nt < 4; nt++)
                            bfr[nt] = *(const bf16x8*)(Bp + kbl * 2048 + q * 512 + (nt * 16 + sub) * 8);
                        #pragma unroll
                        for (int c = 0; c < 2; c++) {
                            if (!act[c]) continue;
                            bf16x8 afr;
                            #pragma unroll
                            for (int z = 0; z < 8; z++) afr[z] = (__bf16)(Lf[c][p2][z] * Li[c]);
                            #pragma unroll
                            for (int nt = 0; nt < 4; nt++)
                                acc[c][nt] = __builtin_amdgcn_mfma_f32_16x16x32_bf16(afr, bfr[nt], acc[c][nt], 0, 0, 0);
                        }
                    }
                }
            } else {                             // concat(L,R): kb 128..131
                bf16x8 A4[2][4];
                #pragma unroll
                for (int c = 0; c < 2; c++) {
                    A4[c][0] = *(const bf16x8*)(Xs + slotL[c] + q * 8);
                    A4[c][1] = *(const bf16x8*)(Xs + slotL[c] + 32 + q * 8);
                    A4[c][2] = *(const bf16x8*)(Xs + slotL[c] + XSTR + q * 8);
                    A4[c][3] = *(const bf16x8*)(Xs + slotL[c] + XSTR + 32 + q * 8);
                }
                #pragma unroll
                for (int kbl = 0; kbl < 4; kbl++) {
                    bf16x8 bfr[4];
                    #pragma unroll
                    for (int nt = 0; nt < 4; nt++)
                        bfr[nt] = *(const bf16x8*)(Bp + kbl * 2048 + q * 512 + (nt * 16 + sub) * 8);
                    #pragma unroll
                    for (int c = 0; c < 2; c++) {
                        if (!act[c]) continue;
                        #pragma unroll
                        for (int nt = 0; nt < 4; nt++)
                            acc[c][nt] = __builtin_amdgcn_mfma_f32_16x16x32_bf16(A4[c][kbl], bfr[nt], acc[c][nt], 0, 0, 0);
                    }
                }
            }
            __syncthreads();   // readers done before buffer reuse / epilogue writes
        }

        // ---- epilogue ----
        if (lv < 5) {
            #pragma unroll
            for (int c = 0; c < 2; c++) {
                if (!act[c]) continue;
                #pragma unroll
                for (int nt = 0; nt < 4; nt++) {
                    int e = nt * 16 + sub;
                    #pragma unroll
                    for (int rr = 0; rr < 4; rr++) {
                        int m = (wave * chpw + c) * 16 + q * 4 + rr;
                        if (m < nodes) {
                            int t = m >> lg, n = m & (cnew - 1);
                            Xs[(t * 64 + n) * XSTR + e] = f2b(tanhf(scrub(acc[c][nt][rr] + biasC[e])));
                        }
                    }
                }
            }
            __syncthreads();   // next level's hoist reads Xs
        } else {
            if (act[0]) {
                #pragma unroll
                for (int nt = 0; nt < 4; nt++) {
                    int e = nt * 16 + sub;
                    #pragma unroll
                    for (int rr = 0; rr < 4; rr++) {
                        int m = q * 4 + rr;      // root: tree index
                        if (m < TPW)
                            g_roots[((size_t)wg * TPW + m) * 64 + e] =
                                f2b(tanhf(scrub(acc[0][nt][rr] + biasC[e])));
                    }
                }
            }
        }
    }
}

// ---------- kernel: final cpr/cprt + leaky_relu + softmax ----------
__global__ __launch_bounds__(256, 2) void k_final(const void* __restrict__ voc_b,
                                                  void* __restrict__ out)
{
    __shared__ __attribute__((aligned(16))) unsigned short Lv[64 * XSTR], Rv[64 * XSTR];
    __shared__ __attribute__((aligned(16))) unsigned short Bs[2][STG];
    __shared__ float actS[64][65];
    __shared__ float smw[7][64];
    __shared__ float smbS[7];
    __shared__ float biasF[64];
    const int tid = threadIdx.x, wg = blockIdx.x;
    const int isb = detect_isb(voc_b);
    if (tid < 64) biasF[tid] = g_biasF[tid];
    if (tid < 7)  smbS[tid] = g_smb[tid];
    for (int z = tid; z < 448; z += 256) smw[z >> 6][z & 63] = g_smw[z];

    {   // stage l and r roots for this WG's 64 items
        int row = tid >> 1, half = tid & 1;
        int item = row & 63; bool isR = row >= 64;
        const unsigned short* src = g_roots + (size_t)((isR ? 1024 : 0) + wg * 64 + item) * 64 + half * 32;
        unsigned short* dst = (isR ? Rv : Lv) + item * XSTR + half * 32;
        const uint4* s4 = (const uint4*)src; uint4* d4 = (uint4*)dst;
        #pragma unroll
        for (int z = 0; z < 4; z++) d4[z] = s4[z];
    }

    uint4 r[4];
    #pragma unroll
    for (int j = 0; j < 4; j++)
        r[j] = *(const uint4*)(g_cprtU + j * 2048 + (size_t)tid * 8);

    __syncthreads();

    const int lane = tid & 63, wave = tid >> 6;
    const int q = lane >> 4, sub = lane & 15;
    const int item = wave * 16 + sub;
    const int rowLo = item * XSTR;

    float Rf[2][8];                              // kron = l[i] * r[j]
    {
        bf16x8 o0 = *(const bf16x8*)(Rv + rowLo + q * 8);
        bf16x8 o1 = *(const bf16x8*)(Rv + rowLo + 32 + q * 8);
        #pragma unroll
        for (int z = 0; z < 8; z++) { Rf[0][z] = (float)o0[z]; Rf[1][z] = (float)o1[z]; }
    }

    f32x4 acc[4];
    #pragma unroll
    for (int nt = 0; nt < 4; nt++)
        #pragma unroll
        for (int z = 0; z < 4; z++) acc[nt][z] = 0.f;

    for (int s = 0; s < NSTAGE; s++) {
        const int par = s & 1;
        #pragma unroll
        for (int j = 0; j < 4; j++)
            *(uint4*)(Bs[par] + j * 2048 + tid * 8) = r[j];
        __syncthreads();
        if (s < NSTAGE - 1) {
            const unsigned short* base = g_cprtU + (size_t)(s + 1) * STG;
            #pragma unroll
            for (int j = 0; j < 4; j++)
                r[j] = *(const uint4*)(base + j * 2048 + tid * 8);
        }
        const unsigned short* Bp = Bs[par];
        if (s < 32) {
            #pragma unroll
            for (int ii = 0; ii < 2; ii++) {
                int i = 2 * s + ii;
                float Li = b2f(Lv[rowLo + i]);
                #pragma unroll
                for (int p2 = 0; p2 < 2; p2++) {
                    int kbl = 2 * ii + p2;
                    bf16x8 bfr[4];
                    #pragma unroll
                    for (int nt = 0; nt < 4; nt++)
                        bfr[nt] = *(const bf16x8*)(Bp + kbl * 2048 + q * 512 + (nt * 16 + sub) * 8);
                    bf16x8 afr;
                    #pragma unroll
                    for (int z = 0; z < 8; z++) afr[z] = (__bf16)(Rf[p2][z] * Li);
                    #pragma unroll
                    for (int nt = 0; nt < 4; nt++)
                        acc[nt] = __builtin_amdgcn_mfma_f32_16x16x32_bf16(afr, bfr[nt], acc[nt], 0, 0, 0);
                }
            }
        } else {                                 // concat(l, r)
            bf16x8 A4[4];
            A4[0] = *(const bf16x8*)(Lv + rowLo + q * 8);
            A4[1] = *(const bf16x8*)(Lv + rowLo + 32 + q * 8);
            A4[2] = *(const bf16x8*)(Rv + rowLo + q * 8);
            A4[3] = *(const bf16x8*)(Rv + rowLo + 32 + q * 8);
            #pragma unroll
            for (int kbl = 0; kbl < 4; kbl++) {
                bf16x8 bfr[4];
                #pragma unroll
                for (int nt = 0; nt < 4; nt++)
                    bfr[nt] = *(const bf16x8*)(Bp + kbl * 2048 + q * 512 + (nt * 16 + sub) * 8);
                #pragma unroll
                for (int nt = 0; nt < 4; nt++)
                    acc[nt] = __builtin_amdgcn_mfma_f32_16x16x32_bf16(A4[kbl], bfr[nt], acc[nt], 0, 0, 0);
            }
        }
        __syncthreads();
    }

    // epilogue: bias + leaky_relu -> LDS
    #pragma unroll
    for (int nt = 0; nt < 4; nt++) {
        int e = nt * 16 + sub;
        #pragma unroll
        for (int rr = 0; rr < 4; rr++) {
            int it = wave * 16 + q * 4 + rr;
            float v = scrub(acc[nt][rr] + biasF[e]);
            v = (v > 0.f) ? v : 0.01f * v;
            actS[it][e] = v;
        }
    }
    __syncthreads();

    if (tid < 64) {
        float lg[7];
        #pragma unroll
        for (int j = 0; j < 7; j++) lg[j] = smbS[j];
        for (int e = 0; e < 64; e++) {
            float a = actS[tid][e];
            #pragma unroll
            for (int j = 0; j < 7; j++) lg[j] += smw[j][e] * a;
        }
        float mx = lg[0];
        #pragma unroll
        for (int j = 1; j < 7; j++) mx = fmaxf(mx, lg[j]);
        float s = 0.f, p[7];
        #pragma unroll
        for (int j = 0; j < 7; j++) { p[j] = expf(lg[j] - mx); s += p[j]; }
        float inv = 1.f / s;
        size_t b = (size_t)wg * 64 + tid;
        if (isb) {
            unsigned short* o = (unsigned short*)out;
            #pragma unroll
            for (int j = 0; j < 7; j++) o[b * 7 + j] = f2b(p[j] * inv);
        } else {
            float* o = (float*)out;
            #pragma unroll
            for (int j = 0; j < 7; j++) o[b * 7 + j] = p[j] * inv;
        }
    }
}

// ---------- host launcher ----------
extern "C" void kernel_launch(void* const* d_in, const int* in_sizes, int n_in,
                              void* d_out, int out_size, void* d_ws, size_t ws_size,
                              hipStream_t stream) {
    const int* lleaf = (const int*)d_in[0];
    const int* rleaf = (const int*)d_in[1];
    const void* voc_w  = d_in[2];
    const void* voc_b  = d_in[3];
    const void* cps_w  = d_in[4];
    const void* cps_b  = d_in[5];
    const void* cpst_w = d_in[6];
    const void* cpst_b = d_in[7];
    const void* cpr_w  = d_in[8];
    const void* cpr_b  = d_in[9];
    const void* cprt_w = d_in[10];
    const void* cprt_b = d_in[11];
    const void* sm_w   = d_in[12];
    const void* sm_b   = d_in[13];

    k_convert<<<512, 256, 0, stream>>>(voc_b, cps_w, cps_b, cpst_w, cpst_b,
                                       cpr_w, cpr_b, cprt_w, cprt_b, sm_w, sm_b);
    k_vocT<<<(VOC + 63) / 64, 256, 0, stream>>>(voc_w, voc_b);
    k_tree<<<2048 / TPW, 512, 0, stream>>>(lleaf, rleaf);
    k_final<<<16, 256, 0, stream>>>(voc_b, (unsigned short*)d_out);
}